// Round 16
// baseline (99.439 us; speedup 1.0000x reference)
//
#include <hip/hip_runtime.h>

// 256 independent LSAP problems (scipy-trajectory-exact Jonker-Volgenant),
// one wave per problem, lane j owns column j and row j's dual state.
// FAST path (on-grid f32 inputs = exact multiples of 2^-23): solver in int32
// scaled by 2^23; per-scan gather is ONE ds_read_b32 from a pre-scaled int
// LDS image (gfx950 has no register-indexed read: v_movrels removed, dynamic
// vector extracts lower via scratch -- R6-R14). Argmin via lane-packed keys
// rp=(r<<6)|lane with a fused v_min_u32_dpp reduction (R9/R10).
// R16: loop ROTATION -- the next row's ds_read is issued speculatively right
// after rj=row4col[jsel] is known, BEFORE the sink test, so the exit branch,
// SR update and u_i readlane execute under the ~120cy LDS load shadow.
// Guard: relaxed r in [0,2^25) else f64/LDS redo. Output bit-identical.

union DU { double d; int i2[2]; };

__device__ inline double readlane_f64(double x, int l) {
    DU a; a.d = x;
    DU o;
    o.i2[0] = __builtin_amdgcn_readlane(a.i2[0], l);
    o.i2[1] = __builtin_amdgcn_readlane(a.i2[1], l);
    return o.d;
}

template <int CTRL>
__device__ inline double dpp_min_f64(double x) {
    DU a; a.d = x;
    DU b;
    b.i2[0] = __builtin_amdgcn_update_dpp(0, a.i2[0], CTRL, 0xF, 0xF, true);
    b.i2[1] = __builtin_amdgcn_update_dpp(0, a.i2[1], CTRL, 0xF, 0xF, true);
    return fmin(x, b.d);
}

// ---------------- fallback: verified round-3 f64 / LDS path ----------------
__device__ void run_lsap_f64(const float* __restrict__ costL, int lane, int c,
                             int& path_r, int& row4col_r, int& col4row_r)
{
    const double INF = __builtin_inf();
    double u_d = 0.0, v_d = 0.0;

    for (int cur_row = 0; cur_row < c; ++cur_row) {
        double minv_d    = INF;
        bool   remaining = true;
        unsigned long long SR = 0ULL;
        int    i       = cur_row;
        double min_val = 0.0;
        int    sink    = -1;

        while (sink < 0) {
            SR |= 1ULL << i;
            const double u_i = readlane_f64(u_d, i);
            const float  cf  = costL[i * 64 + lane];
            double r = min_val + (double)cf;   // numpy order, no FMA
            r = r - u_i;
            r = r - v_d;
            const bool upd = remaining && (r < minv_d);
            minv_d = upd ? r : minv_d;
            path_r = upd ? i : path_r;

            const double key = remaining ? minv_d : INF;
            double k = dpp_min_f64<0xB1>(key);
            k = dpp_min_f64<0x4E>(k);
            k = dpp_min_f64<0x141>(k);
            k = dpp_min_f64<0x140>(k);
            const double m0 = readlane_f64(k, 0);
            const double m1 = readlane_f64(k, 16);
            const double m2 = readlane_f64(k, 32);
            const double m3 = readlane_f64(k, 48);
            const double kmin = fmin(fmin(m0, m1), fmin(m2, m3));
            const unsigned long long eq = __ballot(key == kmin);
            const int jsel = __ffsll(eq) - 1;
            min_val = kmin;
            remaining = remaining && (lane != jsel);
            const int rj = __builtin_amdgcn_readlane(row4col_r, jsel);
            if (rj < 0) sink = jsel; else i = rj;
        }

        {
            const bool scanned_row = (SR >> lane) & 1ULL;
            const int  gidx = col4row_r & 63;
            const double mv_g = __shfl(minv_d, gidx, 64);
            if (lane == cur_row)       u_d += min_val;
            else if (scanned_row)      u_d += min_val - mv_g;
            if (!remaining)            v_d -= min_val - minv_d;
        }
        {
            int jj = sink;
            while (true) {
                const int ii = __builtin_amdgcn_readlane(path_r, jj);
                if (lane == jj) row4col_r = ii;
                const int tmp = __builtin_amdgcn_readlane(col4row_r, ii);
                if (lane == ii) col4row_r = jj;
                jj = tmp;
                if (ii == cur_row) break;
            }
        }
    }
}

__global__ __launch_bounds__(64, 1)
void lsap_solve(const float* __restrict__ cost,
                const float* __restrict__ gt,
                float* __restrict__ out,
                double* __restrict__ partial)
{
    const int b    = blockIdx.x;
    const int lane = threadIdx.x;          // column index (and row index for u)

    __shared__ float costL[64 * 64];       // row-major [row][col], float
    __shared__ int   costI[64 * 64];       // row-major, cost * 2^23 (exact int)
    __shared__ int   ordL[64];

    // ---- stage cost matrix to LDS (coalesced float4) ----
    const float4* cb4 = (const float4*)(cost + (size_t)b * 4096);
    float4*       cl4 = (float4*)costL;
#pragma unroll
    for (int i = 0; i < 16; ++i)
        cl4[i * 64 + lane] = cb4[i * 64 + lane];

    // ---- valid-box count: first all-zero [2,3] box ----
    const float* gb = gt + (size_t)b * 384 + lane * 6;
    bool iszero = true;
#pragma unroll
    for (int k = 0; k < 6; ++k) iszero = iszero && (gb[k] == 0.0f);
    unsigned long long zmask = __ballot(iszero);
    const int c = zmask ? (__ffsll(zmask) - 1) : 64;

    __syncthreads();           // costL visible

    // ---- scaled-int LDS image + on-grid check (prologue, off-chain) ----
    bool ongrid = true;
#pragma unroll
    for (int k = 0; k < 64; ++k) {
        const double h = (double)costL[k * 64 + lane] * 8388608.0;
        ongrid = ongrid && (h >= 0.0) && (h < 16777216.0) && (h == floor(h));
        costI[k * 64 + lane] = (int)h;
    }
    const bool fast = (__ballot(ongrid) == ~0ULL);
    __syncthreads();           // costI visible

    int path_r    = -1;        // path[lane]    (lane as col)
    int row4col_r = -1;        // row4col[lane] (lane as col)
    int col4row_r = -1;        // col4row[lane] (lane as row)
    bool bad = false;

    if (fast) {
        // ---------------- int32-scaled packed-key solver ----------------
        int u_s = 0;               // u[lane] * 2^23   (lane as row)
        int v_s = 0;               // v[lane] * 2^23   (lane as col)
        int negv = 0;              // -v_s, refreshed per augmentation
        const int lane_rm = lane | 0x7FFFFFC0;   // removed-column key
        int rmax = 0, rmin = 0;    // guard accumulators over all relaxed r

        for (int cur_row = 0; cur_row < c; ++cur_row) {
            int  key_s     = 0x7FFFFFFF;   // packed (minv<<6|lane), MAX=unrelaxed
            int  lane_or   = lane;         // low bits; lane_rm once removed
            int  minv_true = 0;            // frozen minv at removal (scaled)
            bool rem_v     = true;         // column still remaining
            unsigned long long SR = 0ULL;
            int  i       = cur_row;        // wave-uniform
            int  min_val = 0;              // scaled, SGPR
            int  sink    = -1;

            // rotated loop: row read pre-issued; next read issued before the
            // exit test so branch/SR/u_i hide under the LDS load latency.
            int cv = costI[(i << 6) + lane];

            while (true) {
                SR |= 1ULL << i;
                const int u_i = __builtin_amdgcn_readlane(u_s, i);
                const int mu  = min_val - u_i;              // SALU, parallel
                const int r   = (cv + negv) + mu;           // exact int
                rmax = r > rmax ? r : rmax;                 // guard (off-chain)
                rmin = r < rmin ? r : rmin;

                const unsigned rp = ((unsigned)r << 6) | (unsigned)lane_or;
                const bool upd = rp < (unsigned)key_s;      // auto-false if removed
                path_r = upd ? i : path_r;                  // off-chain
                key_s  = (int)(upd ? rp : (unsigned)key_s);

                // fused-DPP wave min of packed keys -> gmin (SGPR).
                int kk = key_s;
                int gmin;
                asm("s_nop 1\n\t"
                    "v_min_u32_dpp %0, %0, %0 quad_perm:[1,0,3,2] row_mask:0xf bank_mask:0xf\n\t"
                    "s_nop 1\n\t"
                    "v_min_u32_dpp %0, %0, %0 quad_perm:[2,3,0,1] row_mask:0xf bank_mask:0xf\n\t"
                    "s_nop 1\n\t"
                    "v_min_u32_dpp %0, %0, %0 row_half_mirror row_mask:0xf bank_mask:0xf\n\t"
                    "s_nop 1\n\t"
                    "v_min_u32_dpp %0, %0, %0 row_mirror row_mask:0xf bank_mask:0xf\n\t"
                    "s_nop 1\n\t"
                    "v_min_u32_dpp %0, %0, %0 row_bcast:15 row_mask:0xa bank_mask:0xf\n\t"
                    "s_nop 1\n\t"
                    "v_min_u32_dpp %0, %0, %0 row_bcast:31 row_mask:0xc bank_mask:0xf\n\t"
                    "s_nop 1\n\t"
                    "v_readlane_b32 %1, %0, 63"
                    : "+v"(kk), "=s"(gmin));

                const int jsel = gmin & 63;                 // argmin (np tie-break)
                min_val = (int)((unsigned)gmin >> 6);       // min value, SGPR

                const bool selme = (lane == jsel);          // off-chain updates
                minv_true = selme ? min_val : minv_true;
                key_s     = selme ? lane_rm : key_s;
                lane_or   = selme ? lane_rm : lane_or;
                rem_v     = rem_v && !selme;

                const int rj = __builtin_amdgcn_readlane(row4col_r, jsel);
                // speculative next-row read (rj<0 -> row 63, discarded on exit)
                cv = costI[((rj & 63) << 6) + lane];
                if (rj < 0) { sink = jsel; break; }
                i = rj;
            }

            // ---- dual updates (reference formulas, scaled ints) ----
            {
                const bool scanned_row = (SR >> lane) & 1ULL;
                const int  gidx = col4row_r & 63;               // clamp -1 -> unused
                const int  mv_g = __shfl(minv_true, gidx, 64);  // minv[col4row[lane]]
                if (lane == cur_row)       u_s += min_val;
                else if (scanned_row)      u_s += min_val - mv_g;
                if (!rem_v)                v_s -= min_val - minv_true;
                negv = -v_s;
            }

            // ---- augment along alternating path (predicated lane writes) ----
            {
                int jj = sink;
                while (true) {
                    const int ii = __builtin_amdgcn_readlane(path_r, jj);
                    if (lane == jj) row4col_r = ii;
                    const int tmp = __builtin_amdgcn_readlane(col4row_r, ii);
                    if (lane == ii) col4row_r = jj;
                    jj = tmp;
                    if (ii == cur_row) break;
                }
            }
        }

        // guard: any relaxed r outside [0, 2^25) invalidates packing
        bad = __ballot((rmax >= (1 << 25)) || (rmin < 0)) != 0ULL;
        if (bad) { path_r = -1; row4col_r = -1; col4row_r = -1; }
    }

    if (!fast || bad) {
        run_lsap_f64(costL, lane, c, path_r, row4col_r, col4row_r);
    }

    // ---- ordering = concat(col4row[0:c], sorted unassigned columns) ----
    const bool assigned = (row4col_r >= 0);                 // lane as col
    const unsigned long long amask = __ballot(assigned);
    if (lane < c) ordL[lane] = col4row_r;                   // lane as row
    if (!assigned) {
        const unsigned long long below = (~amask) & ((1ULL << lane) - 1ULL);
        ordL[c + __popcll(below)] = lane;
    }
    __syncthreads();

    const int oc = ordL[lane];
    out[b * 64 + lane] = (float)oc;

    // ---- per-block loss partial: sum_r cost[r, ordering[r]] ----
    double p = (double)costL[lane * 64 + oc];
#pragma unroll
    for (int s = 1; s < 64; s <<= 1) p += __shfl_xor(p, s, 64);
    if (lane == 0) partial[b] = p;
}

__global__ __launch_bounds__(256)
void loss_reduce(const double* __restrict__ partial, float* __restrict__ out,
                 int B)
{
    const int t = threadIdx.x;
    __shared__ double sb[4];
    double p = 0.0;
    for (int idx = t; idx < B; idx += 256) p += partial[idx];
#pragma unroll
    for (int s = 1; s < 64; s <<= 1) p += __shfl_xor(p, s, 64);
    if ((t & 63) == 0) sb[t >> 6] = p;
    __syncthreads();
    if (t == 0)
        out[B * 64] = (float)((sb[0] + sb[1] + sb[2] + sb[3]) / (double)(B * 64));
}

extern "C" void kernel_launch(void* const* d_in, const int* in_sizes, int n_in,
                              void* d_out, int out_size, void* d_ws, size_t ws_size,
                              hipStream_t stream)
{
    const float* cost = (const float*)d_in[0];   // [B,64,64] f32
    const float* gt   = (const float*)d_in[1];   // [B,64,2,3] f32
    float* out        = (float*)d_out;           // [B*64] ordering + [1] loss
    double* partial   = (double*)d_ws;           // B doubles of scratch

    const int B = in_sizes[0] / 4096;            // 64*64 per problem

    lsap_solve<<<B, 64, 0, stream>>>(cost, gt, out, partial);
    loss_reduce<<<1, 256, 0, stream>>>(partial, out, B);
}

// Round 17
// 95.872 us; speedup vs baseline: 1.0372x; 1.0372x over previous
//
#include <hip/hip_runtime.h>

// 256 independent LSAP problems (scipy-trajectory-exact Jonker-Volgenant),
// one wave per problem, lane j owns column j and row j's dual state.
// FAST path (on-grid f32 inputs = exact multiples of 2^-23): solver in int32
// scaled by 2^23; per-scan gather is ONE ds_read_b32 from a pre-scaled int
// LDS image (gfx950 has no register-indexed read: v_movrels removed, dynamic
// vector extracts lower via scratch -- R6-R14). Argmin via lane-packed keys
// rp=(r<<6)|lane with the fused v_min_u32_dpp reduction (R9/R10).
// This is the R15 structure (best measured: 91.5us steady), reverted after
// R16's loop rotation proved null/negative. Chain floor: ~200cy/scan =
// ds_read 120 + DPP reduce ~45 + control ~35; worst problem ~1100 scans.
// Guard: relaxed r in [0,2^25) else f64/LDS redo. Output bit-identical.

union DU { double d; int i2[2]; };

__device__ inline double readlane_f64(double x, int l) {
    DU a; a.d = x;
    DU o;
    o.i2[0] = __builtin_amdgcn_readlane(a.i2[0], l);
    o.i2[1] = __builtin_amdgcn_readlane(a.i2[1], l);
    return o.d;
}

template <int CTRL>
__device__ inline double dpp_min_f64(double x) {
    DU a; a.d = x;
    DU b;
    b.i2[0] = __builtin_amdgcn_update_dpp(0, a.i2[0], CTRL, 0xF, 0xF, true);
    b.i2[1] = __builtin_amdgcn_update_dpp(0, a.i2[1], CTRL, 0xF, 0xF, true);
    return fmin(x, b.d);
}

// ---------------- fallback: verified round-3 f64 / LDS path ----------------
__device__ void run_lsap_f64(const float* __restrict__ costL, int lane, int c,
                             int& path_r, int& row4col_r, int& col4row_r)
{
    const double INF = __builtin_inf();
    double u_d = 0.0, v_d = 0.0;

    for (int cur_row = 0; cur_row < c; ++cur_row) {
        double minv_d    = INF;
        bool   remaining = true;
        unsigned long long SR = 0ULL;
        int    i       = cur_row;
        double min_val = 0.0;
        int    sink    = -1;

        while (sink < 0) {
            SR |= 1ULL << i;
            const double u_i = readlane_f64(u_d, i);
            const float  cf  = costL[i * 64 + lane];
            double r = min_val + (double)cf;   // numpy order, no FMA
            r = r - u_i;
            r = r - v_d;
            const bool upd = remaining && (r < minv_d);
            minv_d = upd ? r : minv_d;
            path_r = upd ? i : path_r;

            const double key = remaining ? minv_d : INF;
            double k = dpp_min_f64<0xB1>(key);
            k = dpp_min_f64<0x4E>(k);
            k = dpp_min_f64<0x141>(k);
            k = dpp_min_f64<0x140>(k);
            const double m0 = readlane_f64(k, 0);
            const double m1 = readlane_f64(k, 16);
            const double m2 = readlane_f64(k, 32);
            const double m3 = readlane_f64(k, 48);
            const double kmin = fmin(fmin(m0, m1), fmin(m2, m3));
            const unsigned long long eq = __ballot(key == kmin);
            const int jsel = __ffsll(eq) - 1;
            min_val = kmin;
            remaining = remaining && (lane != jsel);
            const int rj = __builtin_amdgcn_readlane(row4col_r, jsel);
            if (rj < 0) sink = jsel; else i = rj;
        }

        {
            const bool scanned_row = (SR >> lane) & 1ULL;
            const int  gidx = col4row_r & 63;
            const double mv_g = __shfl(minv_d, gidx, 64);
            if (lane == cur_row)       u_d += min_val;
            else if (scanned_row)      u_d += min_val - mv_g;
            if (!remaining)            v_d -= min_val - minv_d;
        }
        {
            int jj = sink;
            while (true) {
                const int ii = __builtin_amdgcn_readlane(path_r, jj);
                if (lane == jj) row4col_r = ii;
                const int tmp = __builtin_amdgcn_readlane(col4row_r, ii);
                if (lane == ii) col4row_r = jj;
                jj = tmp;
                if (ii == cur_row) break;
            }
        }
    }
}

__global__ __launch_bounds__(64, 1)
void lsap_solve(const float* __restrict__ cost,
                const float* __restrict__ gt,
                float* __restrict__ out,
                double* __restrict__ partial)
{
    const int b    = blockIdx.x;
    const int lane = threadIdx.x;          // column index (and row index for u)

    __shared__ float costL[64 * 64];       // row-major [row][col], float
    __shared__ int   costI[64 * 64];       // row-major, cost * 2^23 (exact int)
    __shared__ int   ordL[64];

    // ---- stage cost matrix to LDS (coalesced float4) ----
    const float4* cb4 = (const float4*)(cost + (size_t)b * 4096);
    float4*       cl4 = (float4*)costL;
#pragma unroll
    for (int i = 0; i < 16; ++i)
        cl4[i * 64 + lane] = cb4[i * 64 + lane];

    // ---- valid-box count: first all-zero [2,3] box ----
    const float* gb = gt + (size_t)b * 384 + lane * 6;
    bool iszero = true;
#pragma unroll
    for (int k = 0; k < 6; ++k) iszero = iszero && (gb[k] == 0.0f);
    unsigned long long zmask = __ballot(iszero);
    const int c = zmask ? (__ffsll(zmask) - 1) : 64;

    __syncthreads();           // costL visible

    // ---- scaled-int LDS image + on-grid check (prologue, off-chain) ----
    bool ongrid = true;
#pragma unroll
    for (int k = 0; k < 64; ++k) {
        const double h = (double)costL[k * 64 + lane] * 8388608.0;
        ongrid = ongrid && (h >= 0.0) && (h < 16777216.0) && (h == floor(h));
        costI[k * 64 + lane] = (int)h;
    }
    const bool fast = (__ballot(ongrid) == ~0ULL);
    __syncthreads();           // costI visible

    int path_r    = -1;        // path[lane]    (lane as col)
    int row4col_r = -1;        // row4col[lane] (lane as col)
    int col4row_r = -1;        // col4row[lane] (lane as row)
    bool bad = false;

    if (fast) {
        // ---------------- int32-scaled packed-key solver ----------------
        int u_s = 0;               // u[lane] * 2^23   (lane as row)
        int v_s = 0;               // v[lane] * 2^23   (lane as col)
        int negv = 0;              // -v_s, refreshed per augmentation
        const int lane_rm = lane | 0x7FFFFFC0;   // removed-column key
        int rmax = 0, rmin = 0;    // guard accumulators over all relaxed r

        for (int cur_row = 0; cur_row < c; ++cur_row) {
            int  key_s     = 0x7FFFFFFF;   // packed (minv<<6|lane), MAX=unrelaxed
            int  lane_or   = lane;         // low bits; lane_rm once removed
            int  minv_true = 0;            // frozen minv at removal (scaled)
            bool rem_v     = true;         // column still remaining
            unsigned long long SR = 0ULL;
            int  i       = cur_row;        // wave-uniform
            int  min_val = 0;              // scaled, SGPR
            int  sink    = -1;

            while (sink < 0) {
                SR |= 1ULL << i;
                const int u_i = __builtin_amdgcn_readlane(u_s, i);
                const int mu  = min_val - u_i;              // SALU, parallel
                // the one chain memory op: ds_read_b32 (2-way alias = free)
                const int cv = costI[(i << 6) + lane];
                const int r  = (cv + negv) + mu;            // exact int
                rmax = r > rmax ? r : rmax;                 // guard (off-chain)
                rmin = r < rmin ? r : rmin;

                const unsigned rp = ((unsigned)r << 6) | (unsigned)lane_or;
                const bool upd = rp < (unsigned)key_s;      // auto-false if removed
                path_r = upd ? i : path_r;                  // off-chain
                key_s  = (int)(upd ? rp : (unsigned)key_s);

                // fused-DPP wave min of packed keys -> gmin (SGPR).
                int kk = key_s;
                int gmin;
                asm("s_nop 1\n\t"
                    "v_min_u32_dpp %0, %0, %0 quad_perm:[1,0,3,2] row_mask:0xf bank_mask:0xf\n\t"
                    "s_nop 1\n\t"
                    "v_min_u32_dpp %0, %0, %0 quad_perm:[2,3,0,1] row_mask:0xf bank_mask:0xf\n\t"
                    "s_nop 1\n\t"
                    "v_min_u32_dpp %0, %0, %0 row_half_mirror row_mask:0xf bank_mask:0xf\n\t"
                    "s_nop 1\n\t"
                    "v_min_u32_dpp %0, %0, %0 row_mirror row_mask:0xf bank_mask:0xf\n\t"
                    "s_nop 1\n\t"
                    "v_min_u32_dpp %0, %0, %0 row_bcast:15 row_mask:0xa bank_mask:0xf\n\t"
                    "s_nop 1\n\t"
                    "v_min_u32_dpp %0, %0, %0 row_bcast:31 row_mask:0xc bank_mask:0xf\n\t"
                    "s_nop 1\n\t"
                    "v_readlane_b32 %1, %0, 63"
                    : "+v"(kk), "=s"(gmin));

                const int jsel = gmin & 63;                 // argmin (np tie-break)
                min_val = (int)((unsigned)gmin >> 6);       // min value, SGPR

                const bool selme = (lane == jsel);          // off-chain updates
                minv_true = selme ? min_val : minv_true;
                key_s     = selme ? lane_rm : key_s;
                lane_or   = selme ? lane_rm : lane_or;
                rem_v     = rem_v && !selme;

                const int rj = __builtin_amdgcn_readlane(row4col_r, jsel);
                if (rj < 0) sink = jsel; else i = rj;
            }

            // ---- dual updates (reference formulas, scaled ints) ----
            {
                const bool scanned_row = (SR >> lane) & 1ULL;
                const int  gidx = col4row_r & 63;               // clamp -1 -> unused
                const int  mv_g = __shfl(minv_true, gidx, 64);  // minv[col4row[lane]]
                if (lane == cur_row)       u_s += min_val;
                else if (scanned_row)      u_s += min_val - mv_g;
                if (!rem_v)                v_s -= min_val - minv_true;
                negv = -v_s;
            }

            // ---- augment along alternating path (predicated lane writes) ----
            {
                int jj = sink;
                while (true) {
                    const int ii = __builtin_amdgcn_readlane(path_r, jj);
                    if (lane == jj) row4col_r = ii;
                    const int tmp = __builtin_amdgcn_readlane(col4row_r, ii);
                    if (lane == ii) col4row_r = jj;
                    jj = tmp;
                    if (ii == cur_row) break;
                }
            }
        }

        // guard: any relaxed r outside [0, 2^25) invalidates packing
        bad = __ballot((rmax >= (1 << 25)) || (rmin < 0)) != 0ULL;
        if (bad) { path_r = -1; row4col_r = -1; col4row_r = -1; }
    }

    if (!fast || bad) {
        run_lsap_f64(costL, lane, c, path_r, row4col_r, col4row_r);
    }

    // ---- ordering = concat(col4row[0:c], sorted unassigned columns) ----
    const bool assigned = (row4col_r >= 0);                 // lane as col
    const unsigned long long amask = __ballot(assigned);
    if (lane < c) ordL[lane] = col4row_r;                   // lane as row
    if (!assigned) {
        const unsigned long long below = (~amask) & ((1ULL << lane) - 1ULL);
        ordL[c + __popcll(below)] = lane;
    }
    __syncthreads();

    const int oc = ordL[lane];
    out[b * 64 + lane] = (float)oc;

    // ---- per-block loss partial: sum_r cost[r, ordering[r]] ----
    double p = (double)costL[lane * 64 + oc];
#pragma unroll
    for (int s = 1; s < 64; s <<= 1) p += __shfl_xor(p, s, 64);
    if (lane == 0) partial[b] = p;
}

__global__ __launch_bounds__(256)
void loss_reduce(const double* __restrict__ partial, float* __restrict__ out,
                 int B)
{
    const int t = threadIdx.x;
    __shared__ double sb[4];
    double p = 0.0;
    for (int idx = t; idx < B; idx += 256) p += partial[idx];
#pragma unroll
    for (int s = 1; s < 64; s <<= 1) p += __shfl_xor(p, s, 64);
    if ((t & 63) == 0) sb[t >> 6] = p;
    __syncthreads();
    if (t == 0)
        out[B * 64] = (float)((sb[0] + sb[1] + sb[2] + sb[3]) / (double)(B * 64));
}

extern "C" void kernel_launch(void* const* d_in, const int* in_sizes, int n_in,
                              void* d_out, int out_size, void* d_ws, size_t ws_size,
                              hipStream_t stream)
{
    const float* cost = (const float*)d_in[0];   // [B,64,64] f32
    const float* gt   = (const float*)d_in[1];   // [B,64,2,3] f32
    float* out        = (float*)d_out;           // [B*64] ordering + [1] loss
    double* partial   = (double*)d_ws;           // B doubles of scratch

    const int B = in_sizes[0] / 4096;            // 64*64 per problem

    lsap_solve<<<B, 64, 0, stream>>>(cost, gt, out, partial);
    loss_reduce<<<1, 256, 0, stream>>>(partial, out, B);
}